// Round 7
// baseline (88.491 us; speedup 1.0000x reference)
//
#include <hip/hip_runtime.h>
#include <math.h>

#define N     1000           // NCLASSES
#define SROW  1000           // sorted-row stride (floats); 4000 B rows, 16B-aligned
#define META  (64 * SROW)    // float offset of metadata region in ws
// meta layout (float-indexed): [META+r] int p ; [META+64+r] unsigned mr ;
//                              [META+128] unsigned done-counter
#define K2_BLOCKS (16 * 64)

// ---- order-preserving float<->uint for atomicMin ----
__device__ inline unsigned fkey(float x) {
    unsigned u = __float_as_uint(x);
    return (u & 0x80000000u) ? ~u : (u | 0x80000000u);
}
__device__ inline float fdecode(unsigned u) {
    return __uint_as_float((u & 0x80000000u) ? (u & 0x7FFFFFFFu) : ~u);
}

// ============ K1': counting-rank + scatter (full-chip, no sort) =============
// grid (4, 64) x 512 threads. Block (m,r) owns elements [250m, 250m+250).
// Thread pair (2i,2i+1) shares element e=250m+i; each half counts 500 keys.
// rank_e = #{j: key_j > key_e}, key = (fkey(v)<<32) | (999-idx)  -- exact,
// stable-descending tie order, a permutation. sorted[rank]=v scatter to ws.
__global__ __launch_bounds__(512) void k1_rank(
    const float* __restrict__ mat, const int* __restrict__ target,
    float* __restrict__ ws)
{
    __shared__ unsigned long long skey[N];

    const int t = threadIdx.x;
    const int m = blockIdx.x;
    const int r = blockIdx.y;
    const float* row = mat + r * N;
    const int tgt = target[r];

    for (int i = t; i < N; i += 512) {
        unsigned u  = __float_as_uint(row[i]);
        unsigned fk = (u & 0x80000000u) ? ~u : (u | 0x80000000u);
        skey[i] = ((unsigned long long)fk << 32) | (unsigned)(N - 1 - i);
    }
    if (m == 0 && t == 0) {
        ((unsigned*)ws)[META + 64 + r] = 0xFFFFFFFFu;   // mr sentinel (> any key)
        if (r == 0) ((unsigned*)ws)[META + 128] = 0u;   // done counter
    }
    __syncthreads();

    const int e = m * 250 + (t >> 1);   // element index (t<500)
    const int h = t & 1;                // key-half
    int c = 0;
    if (t < 500) {
        const unsigned long long mykey = skey[e];
        const int jb = h * 500;
        #pragma unroll 8
        for (int jj = 0; jj < 500; ++jj)
            c += (skey[jb + jj] > mykey);
    }
    c += __shfl_xor(c, 1);              // full rank in both halves
    if (t < 500 && h == 0) {
        ws[r * SROW + c] = row[e];      // scatter into sorted position
        if (e == tgt) ((int*)ws)[META + r] = c;   // p = rank of target
    }
}

// ===== K2': per-block scan + min-max + fused loss (last-block-done) =========
// grid (16, 64) x 256 threads. Block (m,r) handles j in [64m, 64m+64).
// Each block re-derives S[0..1000] from the sorted row (cheap, replicated).
__global__ __launch_bounds__(256) void k2_scan_minmax(
    float* __restrict__ ws, float* __restrict__ out)
{
    __shared__ float Sloc[N + 1];
    __shared__ float rtab[N];
    __shared__ float maxh[256];
    __shared__ float wtot[4];
    __shared__ int   amLast;

    const int t    = threadIdx.x;
    const int lane = t & 63;
    const int w    = t >> 6;
    const int m    = blockIdx.x;
    const int r    = blockIdx.y;
    const int p    = ((const int*)ws)[META + r];
    const int j0   = m * 64;
    unsigned* mr   = (unsigned*)ws + META + 64;
    unsigned* done = (unsigned*)ws + META + 128;

    if (j0 <= p) {
        const float* srow = ws + r * SROW;
        // ---- load sorted row (float4) + block scan -> Sloc[0..1000] ----
        float4 v = make_float4(0.f, 0.f, 0.f, 0.f);
        if (t < 250) v = ((const float4*)srow)[t];
        float l1 = v.x + v.y, l2 = l1 + v.z, l3 = l2 + v.w;
        float incl = l3;
        #pragma unroll
        for (int off = 1; off < 64; off <<= 1) {
            float y = __shfl_up(incl, off);
            if (lane >= off) incl += y;
        }
        if (lane == 63) wtot[w] = incl;
        for (int d = t; d < N; d += 256) rtab[d] = 1.0f / (float)(d + 1);
        __syncthreads();
        float base = 0.f;
        #pragma unroll
        for (int u = 0; u < 4; ++u) { float x = wtot[u]; if (u < w) base += x; }
        float ex = base + incl - l3;            // sum of sorted[0..4t-1]
        if (t <= 250) Sloc[4 * t] = ex;         // t=250 writes Sloc[1000]
        if (t < 250) {
            Sloc[4 * t + 1] = ex + v.x;
            Sloc[4 * t + 2] = ex + l1;
            Sloc[4 * t + 3] = ex + l2;
        }
        __syncthreads();

        // ---- min-max: sol_p = min_j max_k [(S[k+1]-S[j])/(k-j+1)+(j+k)/2-N]
        const int len = N - p;
        const int j   = j0 + lane;
        const int jc  = (j <= p) ? j : p;       // clamp; clamped lanes discarded
        const int k0  = (w * len) >> 2;
        const int k1  = ((w + 1) * len) >> 2;
        const float  Sj = Sloc[jc];
        const float* sp = &Sloc[p + 1 + k0];    // wave-uniform -> broadcast
        const float* rp = &rtab[p + k0 - jc];   // stride-1 across lanes
        float cc   = 0.5f * (float)(jc + p + k0) - (float)N;
        float maxv = -INFINITY;
        #pragma unroll 8
        for (int it = 0; it < k1 - k0; ++it) {
            float mv = fmaf(sp[it] - Sj, rp[it], cc);
            maxv = fmaxf(maxv, mv);
            cc += 0.5f;                         // exact (multiples of 0.5)
        }
        maxh[t] = maxv;
        __syncthreads();
        if (t < 64) {                           // combine quarters + min-reduce
            float mv = fmaxf(fmaxf(maxh[t], maxh[t + 64]),
                             fmaxf(maxh[t + 128], maxh[t + 192]));
            float minv = (j0 + t <= p) ? mv : INFINITY;
            #pragma unroll
            for (int off = 32; off; off >>= 1)
                minv = fminf(minv, __shfl_down(minv, off));
            if (t == 0) atomicMin(&mr[r], fkey(minv));
        }
    }

    // ---- completion counter; last block computes the loss ----
    if (t == 0) {
        __threadfence();                        // order atomicMin before counter
        unsigned old = atomicAdd(done, 1u);
        amLast = (old == K2_BLOCKS - 1);
    }
    __syncthreads();
    if (amLast && t < 64) {
        float sol  = fdecode(atomicAdd(&mr[t], 0u));    // coherent read
        int   pr   = ((const int*)ws)[META + t];
        float tval = ws[t * SROW + pr];                 // sorted[p] == target val
        float loss = fmaxf(0.0f, (float)(N - 5 + 1) - (tval - sol));
        #pragma unroll
        for (int off = 32; off; off >>= 1) loss += __shfl_down(loss, off);
        if (t == 0) out[0] = loss / 64.0f;
    }
}

// ===================== fallback: monolithic (R4) ============================
__global__ __launch_bounds__(512) void topk_loss_mono(
    const float* __restrict__ mat, const int* __restrict__ target,
    float* __restrict__ d_out, int nrows)
{
    __shared__ float S[1025];
    __shared__ float rcp[N];
    __shared__ float sx[1024];
    __shared__ float wtot[8];
    __shared__ float red[8];
    __shared__ int   cnt_sh;

    const int tid  = threadIdx.x;
    const int lane = tid & 63;
    const int w    = tid >> 6;
    const int i0   = (w << 7) + lane;
    const int i1   = i0 + 64;
    const float* row = mat + blockIdx.x * N;
    const int   tgt  = target[blockIdx.x];
    const float tval = row[tgt];

    float r0 = row[i0];
    float r1 = (i1 < N) ? row[i1] : -INFINITY;
    if (tid == 0) cnt_sh = 0;
    rcp[tid] = 1.0f / (float)(tid + 1);
    if (tid + 512 < N) rcp[tid + 512] = 1.0f / (float)(tid + 512 + 1);

    int lc = ((r0 > tval) || (r0 == tval && i0 < tgt))
           + ((r1 > tval) || (r1 == tval && i1 < tgt));
    #pragma unroll
    for (int off = 32; off; off >>= 1) lc += __shfl_down(lc, off);
    __syncthreads();
    if (lane == 0 && lc) atomicAdd(&cnt_sh, lc);

    auto cas_shfl = [&](float& rr, int i, unsigned k, unsigned j) {
        float o = __shfl_xor(rr, (int)j);
        bool lower = ((lane & (int)j) == 0);
        bool desc  = ((i & (int)k) == 0);
        rr = (lower == desc) ? fmaxf(rr, o) : fminf(rr, o);
    };
    #pragma unroll
    for (unsigned k = 2; k <= 64; k <<= 1)
        #pragma unroll
        for (unsigned j = k >> 1; j; j >>= 1) { cas_shfl(r0, i0, k, j); cas_shfl(r1, i1, k, j); }
    #pragma unroll
    for (unsigned k = 128; k <= 1024; k <<= 1) {
        #pragma unroll
        for (unsigned j = k >> 1; j >= 128; j >>= 1) {
            __syncthreads();
            sx[i0] = r0; sx[i1] = r1;
            __syncthreads();
            float o0 = sx[i0 ^ (int)j], o1 = sx[i1 ^ (int)j];
            bool lower = ((i0 & (int)j) == 0);
            bool desc  = ((i0 & (int)k) == 0);
            r0 = (lower == desc) ? fmaxf(r0, o0) : fminf(r0, o0);
            r1 = (lower == desc) ? fmaxf(r1, o1) : fminf(r1, o1);
        }
        {
            bool desc = ((i0 & (int)k) == 0);
            float a = fmaxf(r0, r1), b = fminf(r0, r1);
            r0 = desc ? a : b;
            r1 = desc ? b : a;
        }
        #pragma unroll
        for (unsigned j = 32; j; j >>= 1) { cas_shfl(r0, i0, k, j); cas_shfl(r1, i1, k, j); }
    }

    if (i1 >= N) r1 = 0.0f;
    float incl0 = r0;
    #pragma unroll
    for (int off = 1; off < 64; off <<= 1) {
        float y = __shfl_up(incl0, off);
        if (lane >= off) incl0 += y;
    }
    float tot0 = __shfl(incl0, 63);
    float incl1 = r1;
    #pragma unroll
    for (int off = 1; off < 64; off <<= 1) {
        float y = __shfl_up(incl1, off);
        if (lane >= off) incl1 += y;
    }
    if (lane == 63) wtot[w] = incl0 + incl1;
    __syncthreads();
    float base = 0.0f;
    #pragma unroll
    for (int u = 0; u < 8; ++u) { float t = wtot[u]; if (u < w) base += t; }
    if (tid == 0) S[0] = 0.0f;
    S[i0 + 1] = base + incl0;
    S[i1 + 1] = base + tot0 + incl1;
    __syncthreads();

    const int p   = cnt_sh;
    const int len = N - p;
    float minv = INFINITY;
    for (int j = tid; j <= p; j += 512) {
        const float  Sj = S[j];
        const float* Sp = &S[p + 1];
        const float* rp = &rcp[p - j];
        const float  cj = 0.5f * (float)(j + p) - (float)N;
        float maxv = -INFINITY;
        #pragma unroll 8
        for (int it = 0; it < len; ++it) {
            float mm = fmaf(Sp[it] - Sj, rp[it], cj + 0.5f * (float)it);
            maxv = fmaxf(maxv, mm);
        }
        minv = fminf(minv, maxv);
    }
    #pragma unroll
    for (int off = 32; off; off >>= 1) minv = fminf(minv, __shfl_down(minv, off));
    if (lane == 0) red[w] = minv;
    __syncthreads();
    if (tid == 0) {
        float sol = red[0];
        #pragma unroll
        for (int u = 1; u < 8; ++u) sol = fminf(sol, red[u]);
        float rank_label = tval - sol;
        float loss = fmaxf(0.0f, (float)(N - 5 + 1) - rank_label);
        atomicAdd(d_out, loss / (float)nrows);
    }
}

extern "C" void kernel_launch(void* const* d_in, const int* in_sizes, int n_in,
                              void* d_out, int out_size, void* d_ws, size_t ws_size,
                              hipStream_t stream) {
    (void)n_in;
    const float* mat    = (const float*)d_in[0];
    const int*   target = (const int*)d_in[1];
    float*       out    = (float*)d_out;
    const int    nrows  = in_sizes[1];   // 64

    const size_t need = (size_t)(META + 192) * sizeof(float);
    if (nrows == 64 && ws_size >= need) {
        float* ws = (float*)d_ws;
        dim3 g1(4, 64);
        k1_rank<<<g1, 512, 0, stream>>>(mat, target, ws);
        dim3 g2(16, 64);
        k2_scan_minmax<<<g2, 256, 0, stream>>>(ws, out);
    } else {
        hipMemsetAsync(out, 0, sizeof(float) * out_size, stream);
        topk_loss_mono<<<nrows, 512, 0, stream>>>(mat, target, out, nrows);
    }
}

// Round 8
// 79.332 us; speedup vs baseline: 1.1155x; 1.1155x over previous
//
#include <hip/hip_runtime.h>
#include <math.h>

#define N      1000           // NCLASSES
#define NTH1   512            // K1: 8 waves; wave w owns positions [128w,128w+128)
#define NTH2   256            // K2: 64 j-lanes x 4 k-quarters
#define MSLICE 16             // K2 blocks per row
#define SROW   1008           // ws row stride (floats); S[0..1000] only (guarded)
#define META   (64 * SROW)    // float offset of metadata
// meta: [META+r] int p | [META+64+r] tval | [META+128+r] unsigned mr |
//       [META+192] unsigned done-counter
#define K2_BLOCKS (MSLICE * 64)

// ---- order-preserving float<->uint for atomicMin ----
__device__ inline unsigned fkey(float x) {
    unsigned u = __float_as_uint(x);
    return (u & 0x80000000u) ? ~u : (u | 0x80000000u);
}
__device__ inline float fdecode(unsigned u) {
    return __uint_as_float((u & 0x80000000u) ? (u & 0x7FFFFFFFu) : ~u);
}

// ===================== K1: sort + prefix-scan + rank ========================
__global__ __launch_bounds__(NTH1) void k1_sort_scan(
    const float* __restrict__ mat, const int* __restrict__ target,
    float* __restrict__ ws)
{
    __shared__ float sx[2][1024];    // double-buffered exchange: 1 barrier/stage
    __shared__ float wtot[8];
    __shared__ int   cnt_sh;

    const int tid  = threadIdx.x;
    const int lane = tid & 63;
    const int w    = tid >> 6;
    const int i0   = (w << 7) + lane;
    const int i1   = i0 + 64;
    const int r    = blockIdx.x;
    const float* row = mat + r * N;
    const int   tgt  = target[r];
    const float tval = row[tgt];

    float r0 = row[i0];                          // i0 <= 959 < N
    float r1 = (i1 < N) ? row[i1] : -INFINITY;
    if (tid == 0) cnt_sh = 0;

    // stable descending-sort position of the target
    int lc = ((r0 > tval) || (r0 == tval && i0 < tgt))
           + ((r1 > tval) || (r1 == tval && i1 < tgt));
    #pragma unroll
    for (int off = 32; off; off >>= 1) lc += __shfl_down(lc, off);
    __syncthreads();                             // cnt_sh=0 visible
    if (lane == 0 && lc) atomicAdd(&cnt_sh, lc);

    // bitonic sort, descending (shuffle j<=32, register j=64, LDS j>=128)
    auto cas_shfl = [&](float& rr, int i, unsigned k, unsigned j) {
        float o = __shfl_xor(rr, (int)j);
        bool lower = ((lane & (int)j) == 0);
        bool desc  = ((i & (int)k) == 0);
        rr = (lower == desc) ? fmaxf(rr, o) : fminf(rr, o);
    };
    #pragma unroll
    for (unsigned k = 2; k <= 64; k <<= 1)
        #pragma unroll
        for (unsigned j = k >> 1; j; j >>= 1) { cas_shfl(r0, i0, k, j); cas_shfl(r1, i1, k, j); }
    int buf = 0;
    #pragma unroll
    for (unsigned k = 128; k <= 1024; k <<= 1) {
        #pragma unroll
        for (unsigned j = k >> 1; j >= 128; j >>= 1) {
            // double-buffer: stage-s reads of buf finish before any wave passes
            // stage-(s+1)'s barrier to rewrite it -> single barrier per stage
            sx[buf][i0] = r0; sx[buf][i1] = r1;
            __syncthreads();
            float o0 = sx[buf][i0 ^ (int)j], o1 = sx[buf][i1 ^ (int)j];
            buf ^= 1;
            bool lower = ((i0 & (int)j) == 0);   // same for i1 (j>=128)
            bool desc  = ((i0 & (int)k) == 0);   // same for i1 (k>=256)
            r0 = (lower == desc) ? fmaxf(r0, o0) : fminf(r0, o0);
            r1 = (lower == desc) ? fmaxf(r1, o1) : fminf(r1, o1);
        }
        {   // j == 64: in-lane register swap
            bool desc = ((i0 & (int)k) == 0);
            float a = fmaxf(r0, r1), b = fminf(r0, r1);
            r0 = desc ? a : b;
            r1 = desc ? b : a;
        }
        #pragma unroll
        for (unsigned j = 32; j; j >>= 1) { cas_shfl(r0, i0, k, j); cas_shfl(r1, i1, k, j); }
    }

    // prefix sums (shuffle scans); -inf pads -> 0
    if (i1 >= N) r1 = 0.0f;
    float incl0 = r0;
    #pragma unroll
    for (int off = 1; off < 64; off <<= 1) {
        float y = __shfl_up(incl0, off);
        if (lane >= off) incl0 += y;
    }
    float tot0 = __shfl(incl0, 63);
    float incl1 = r1;
    #pragma unroll
    for (int off = 1; off < 64; off <<= 1) {
        float y = __shfl_up(incl1, off);
        if (lane >= off) incl1 += y;
    }
    if (lane == 63) wtot[w] = incl0 + incl1;
    __syncthreads();
    float base = 0.0f;
    #pragma unroll
    for (int u = 0; u < 8; ++u) { float t = wtot[u]; if (u < w) base += t; }

    float* Sg = ws + r * SROW;
    if (tid == 0) Sg[0] = 0.0f;
    Sg[i0 + 1] = base + incl0;                   // i0+1 <= 960 < SROW
    if (i1 < N) Sg[i1 + 1] = base + tot0 + incl1;   // only S[1..1000]
    if (tid == 0) {
        ((int*)ws)[META + r]            = cnt_sh;        // p
        ws[META + 64 + r]               = tval;
        ((unsigned*)ws)[META + 128 + r] = 0xFFFFFFFFu;   // mr sentinel (+max key)
        if (r == 0) ((unsigned*)ws)[META + 192] = 0u;    // done counter
    }
}

// ========== K2: min-max at position p + fused loss (last-block-done) ========
__global__ __launch_bounds__(NTH2) void k2_minmax(
    float* __restrict__ ws, float* __restrict__ out)
{
    __shared__ float Sloc[N];    // S[p+1 .. N]
    __shared__ float rtab[N];    // 1/(d+1)
    __shared__ float maxh[NTH2];
    __shared__ int   amLast;

    const int r  = blockIdx.y;
    const int m  = blockIdx.x;
    const int t  = threadIdx.x;
    const int p  = ((const int*)ws)[META + r];
    const int j0 = m * 64;
    unsigned* mr   = (unsigned*)ws + META + 128;
    unsigned* done = (unsigned*)ws + META + 192;

    if (j0 <= p) {
        const int len = N - p;
        const float* Srow = ws + r * SROW;
        const int jl = t & 63;
        const int j  = j0 + jl;
        const float Sj = (j <= p) ? Srow[j] : 0.0f;   // hoisted global load

        for (int i = t; i < len; i += NTH2) Sloc[i] = Srow[p + 1 + i];
        for (int d = t; d < N; d += NTH2) rtab[d] = 1.0f / (float)(d + 1);
        __syncthreads();

        const int q  = t >> 6;                 // wave-uniform k-quarter
        const int k0 = (q * len) >> 2;
        const int k1 = ((q + 1) * len) >> 2;
        float maxv = -INFINITY;
        if (j <= p) {
            const float* sp = &Sloc[k0];       // wave-uniform addr -> broadcast
            const float* rp = &rtab[p + k0 - j];  // stride-1 across lanes
            float c = 0.5f * (float)(j + p + k0) - (float)N;  // (j+k)/2 - N
            #pragma unroll 8
            for (int it = 0; it < k1 - k0; ++it) {
                float mval = fmaf(sp[it] - Sj, rp[it], c);
                maxv = fmaxf(maxv, mval);
                c += 0.5f;                     // exact (multiples of 0.5)
            }
        }
        maxh[t] = maxv;
        __syncthreads();
        if (t < 64) {                          // combine quarters + min-reduce
            float mv = fmaxf(fmaxf(maxh[t], maxh[t + 64]),
                             fmaxf(maxh[t + 128], maxh[t + 192]));
            float minv = (j0 + t <= p) ? mv : INFINITY;
            #pragma unroll
            for (int off = 32; off; off >>= 1)
                minv = fminf(minv, __shfl_down(minv, off));
            if (t == 0) atomicMin(&mr[r], fkey(minv));
        }
    }

    // ---- completion counter; last block computes the loss ----
    if (t == 0) {
        __threadfence();                       // order atomicMin before counter
        amLast = (atomicAdd(done, 1u) == K2_BLOCKS - 1);
    }
    __syncthreads();
    if (amLast && t < 64) {
        float sol  = fdecode(atomicAdd(&mr[t], 0u));   // coherent read
        float tval = ws[META + 64 + t];
        float loss = fmaxf(0.0f, (float)(N - 5 + 1) - (tval - sol));
        #pragma unroll
        for (int off = 32; off; off >>= 1) loss += __shfl_down(loss, off);
        if (t == 0) out[0] = loss / 64.0f;
    }
}

// ===================== fallback: monolithic (R4) ============================
__global__ __launch_bounds__(NTH1) void topk_loss_mono(
    const float* __restrict__ mat, const int* __restrict__ target,
    float* __restrict__ d_out, int nrows)
{
    __shared__ float S[1025];
    __shared__ float rcp[N];
    __shared__ float sx[1024];
    __shared__ float wtot[8];
    __shared__ float red[8];
    __shared__ int   cnt_sh;

    const int tid  = threadIdx.x;
    const int lane = tid & 63;
    const int w    = tid >> 6;
    const int i0   = (w << 7) + lane;
    const int i1   = i0 + 64;
    const float* row = mat + blockIdx.x * N;
    const int   tgt  = target[blockIdx.x];
    const float tval = row[tgt];

    float r0 = row[i0];
    float r1 = (i1 < N) ? row[i1] : -INFINITY;
    if (tid == 0) cnt_sh = 0;
    rcp[tid] = 1.0f / (float)(tid + 1);
    if (tid + NTH1 < N) rcp[tid + NTH1] = 1.0f / (float)(tid + NTH1 + 1);

    int lc = ((r0 > tval) || (r0 == tval && i0 < tgt))
           + ((r1 > tval) || (r1 == tval && i1 < tgt));
    #pragma unroll
    for (int off = 32; off; off >>= 1) lc += __shfl_down(lc, off);
    __syncthreads();
    if (lane == 0 && lc) atomicAdd(&cnt_sh, lc);

    auto cas_shfl = [&](float& rr, int i, unsigned k, unsigned j) {
        float o = __shfl_xor(rr, (int)j);
        bool lower = ((lane & (int)j) == 0);
        bool desc  = ((i & (int)k) == 0);
        rr = (lower == desc) ? fmaxf(rr, o) : fminf(rr, o);
    };
    #pragma unroll
    for (unsigned k = 2; k <= 64; k <<= 1)
        #pragma unroll
        for (unsigned j = k >> 1; j; j >>= 1) { cas_shfl(r0, i0, k, j); cas_shfl(r1, i1, k, j); }
    #pragma unroll
    for (unsigned k = 128; k <= 1024; k <<= 1) {
        #pragma unroll
        for (unsigned j = k >> 1; j >= 128; j >>= 1) {
            __syncthreads();
            sx[i0] = r0; sx[i1] = r1;
            __syncthreads();
            float o0 = sx[i0 ^ (int)j], o1 = sx[i1 ^ (int)j];
            bool lower = ((i0 & (int)j) == 0);
            bool desc  = ((i0 & (int)k) == 0);
            r0 = (lower == desc) ? fmaxf(r0, o0) : fminf(r0, o0);
            r1 = (lower == desc) ? fmaxf(r1, o1) : fminf(r1, o1);
        }
        {
            bool desc = ((i0 & (int)k) == 0);
            float a = fmaxf(r0, r1), b = fminf(r0, r1);
            r0 = desc ? a : b;
            r1 = desc ? b : a;
        }
        #pragma unroll
        for (unsigned j = 32; j; j >>= 1) { cas_shfl(r0, i0, k, j); cas_shfl(r1, i1, k, j); }
    }

    if (i1 >= N) r1 = 0.0f;
    float incl0 = r0;
    #pragma unroll
    for (int off = 1; off < 64; off <<= 1) {
        float y = __shfl_up(incl0, off);
        if (lane >= off) incl0 += y;
    }
    float tot0 = __shfl(incl0, 63);
    float incl1 = r1;
    #pragma unroll
    for (int off = 1; off < 64; off <<= 1) {
        float y = __shfl_up(incl1, off);
        if (lane >= off) incl1 += y;
    }
    if (lane == 63) wtot[w] = incl0 + incl1;
    __syncthreads();
    float base = 0.0f;
    #pragma unroll
    for (int u = 0; u < 8; ++u) { float t = wtot[u]; if (u < w) base += t; }
    if (tid == 0) S[0] = 0.0f;
    S[i0 + 1] = base + incl0;
    S[i1 + 1] = base + tot0 + incl1;
    __syncthreads();

    const int p   = cnt_sh;
    const int len = N - p;
    float minv = INFINITY;
    for (int j = tid; j <= p; j += NTH1) {
        const float  Sj = S[j];
        const float* Sp = &S[p + 1];
        const float* rp = &rcp[p - j];
        const float  cj = 0.5f * (float)(j + p) - (float)N;
        float maxv = -INFINITY;
        #pragma unroll 8
        for (int it = 0; it < len; ++it) {
            float mm = fmaf(Sp[it] - Sj, rp[it], cj + 0.5f * (float)it);
            maxv = fmaxf(maxv, mm);
        }
        minv = fminf(minv, maxv);
    }
    #pragma unroll
    for (int off = 32; off; off >>= 1) minv = fminf(minv, __shfl_down(minv, off));
    if (lane == 0) red[w] = minv;
    __syncthreads();
    if (tid == 0) {
        float sol = red[0];
        #pragma unroll
        for (int u = 1; u < 8; ++u) sol = fminf(sol, red[u]);
        float rank_label = tval - sol;
        float loss = fmaxf(0.0f, (float)(N - 5 + 1) - rank_label);
        atomicAdd(d_out, loss / (float)nrows);
    }
}

extern "C" void kernel_launch(void* const* d_in, const int* in_sizes, int n_in,
                              void* d_out, int out_size, void* d_ws, size_t ws_size,
                              hipStream_t stream) {
    (void)n_in;
    const float* mat    = (const float*)d_in[0];
    const int*   target = (const int*)d_in[1];
    float*       out    = (float*)d_out;
    const int    nrows  = in_sizes[1];   // 64

    const size_t need = (size_t)(META + 256) * sizeof(float);
    if (nrows == 64 && ws_size >= need) {
        float* ws = (float*)d_ws;
        k1_sort_scan<<<nrows, NTH1, 0, stream>>>(mat, target, ws);
        dim3 g2(MSLICE, nrows);
        k2_minmax<<<g2, NTH2, 0, stream>>>(ws, out);
    } else {
        hipMemsetAsync(out, 0, sizeof(float) * out_size, stream);
        topk_loss_mono<<<nrows, NTH1, 0, stream>>>(mat, target, out, nrows);
    }
}

// Round 9
// 68.019 us; speedup vs baseline: 1.3010x; 1.1663x over previous
//
#include <hip/hip_runtime.h>
#include <math.h>

#define N      1000           // NCLASSES
#define NTH1   512            // K1: 8 waves; wave w owns positions [128w,128w+128)
#define NTH2   256            // K2: 64 j-lanes x 4 k-quarters
#define MSLICE 16             // K2 blocks per row
#define SROW   1008           // ws row stride (floats); S[0..1000] only (guarded)
#define META   (64 * SROW)    // float offset of metadata
// meta: [META+r] int p | [META+64+r] tval | [META+128+r] unsigned mr
// NOTE (R8 post-mortem): no done-counter / no __threadfence fused tail --
// 1024 device-scope fences + same-address atomic storm cost ~+9us vs a
// separate 1-block K3 dispatch. Kernel boundaries provide the visibility.

// ---- order-preserving float<->uint for atomicMin ----
__device__ inline unsigned fkey(float x) {
    unsigned u = __float_as_uint(x);
    return (u & 0x80000000u) ? ~u : (u | 0x80000000u);
}
__device__ inline float fdecode(unsigned u) {
    return __uint_as_float((u & 0x80000000u) ? (u & 0x7FFFFFFFu) : ~u);
}

// ===================== K1: sort + prefix-scan + rank ========================
__global__ __launch_bounds__(NTH1) void k1_sort_scan(
    const float* __restrict__ mat, const int* __restrict__ target,
    float* __restrict__ ws)
{
    __shared__ float sx[2][1024];    // double-buffered exchange: 1 barrier/stage
    __shared__ float wtot[8];
    __shared__ int   cnt_sh;

    const int tid  = threadIdx.x;
    const int lane = tid & 63;
    const int w    = tid >> 6;
    const int i0   = (w << 7) + lane;
    const int i1   = i0 + 64;
    const int r    = blockIdx.x;
    const float* row = mat + r * N;
    const int   tgt  = target[r];
    const float tval = row[tgt];

    float r0 = row[i0];                          // i0 <= 959 < N
    float r1 = (i1 < N) ? row[i1] : -INFINITY;
    if (tid == 0) cnt_sh = 0;

    // stable descending-sort position of the target
    int lc = ((r0 > tval) || (r0 == tval && i0 < tgt))
           + ((r1 > tval) || (r1 == tval && i1 < tgt));
    #pragma unroll
    for (int off = 32; off; off >>= 1) lc += __shfl_down(lc, off);
    __syncthreads();                             // cnt_sh=0 visible
    if (lane == 0 && lc) atomicAdd(&cnt_sh, lc);

    // bitonic sort, descending (shuffle j<=32, register j=64, LDS j>=128)
    auto cas_shfl = [&](float& rr, int i, unsigned k, unsigned j) {
        float o = __shfl_xor(rr, (int)j);
        bool lower = ((lane & (int)j) == 0);
        bool desc  = ((i & (int)k) == 0);
        rr = (lower == desc) ? fmaxf(rr, o) : fminf(rr, o);
    };
    #pragma unroll
    for (unsigned k = 2; k <= 64; k <<= 1)
        #pragma unroll
        for (unsigned j = k >> 1; j; j >>= 1) { cas_shfl(r0, i0, k, j); cas_shfl(r1, i1, k, j); }
    int buf = 0;
    #pragma unroll
    for (unsigned k = 128; k <= 1024; k <<= 1) {
        #pragma unroll
        for (unsigned j = k >> 1; j >= 128; j >>= 1) {
            // double-buffer: stage-s reads of buf retire (lgkmcnt in barrier)
            // before any wave passes stage-(s+1)'s barrier to rewrite it
            sx[buf][i0] = r0; sx[buf][i1] = r1;
            __syncthreads();
            float o0 = sx[buf][i0 ^ (int)j], o1 = sx[buf][i1 ^ (int)j];
            buf ^= 1;
            bool lower = ((i0 & (int)j) == 0);   // same for i1 (j>=128)
            bool desc  = ((i0 & (int)k) == 0);   // same for i1 (k>=256)
            r0 = (lower == desc) ? fmaxf(r0, o0) : fminf(r0, o0);
            r1 = (lower == desc) ? fmaxf(r1, o1) : fminf(r1, o1);
        }
        {   // j == 64: in-lane register swap
            bool desc = ((i0 & (int)k) == 0);
            float a = fmaxf(r0, r1), b = fminf(r0, r1);
            r0 = desc ? a : b;
            r1 = desc ? b : a;
        }
        #pragma unroll
        for (unsigned j = 32; j; j >>= 1) { cas_shfl(r0, i0, k, j); cas_shfl(r1, i1, k, j); }
    }

    // prefix sums (shuffle scans); -inf pads -> 0
    if (i1 >= N) r1 = 0.0f;
    float incl0 = r0;
    #pragma unroll
    for (int off = 1; off < 64; off <<= 1) {
        float y = __shfl_up(incl0, off);
        if (lane >= off) incl0 += y;
    }
    float tot0 = __shfl(incl0, 63);
    float incl1 = r1;
    #pragma unroll
    for (int off = 1; off < 64; off <<= 1) {
        float y = __shfl_up(incl1, off);
        if (lane >= off) incl1 += y;
    }
    if (lane == 63) wtot[w] = incl0 + incl1;
    __syncthreads();
    float base = 0.0f;
    #pragma unroll
    for (int u = 0; u < 8; ++u) { float t = wtot[u]; if (u < w) base += t; }

    float* Sg = ws + r * SROW;
    if (tid == 0) Sg[0] = 0.0f;
    Sg[i0 + 1] = base + incl0;                   // i0+1 <= 960 < SROW
    if (i1 < N) Sg[i1 + 1] = base + tot0 + incl1;   // only S[1..1000]
    if (tid == 0) {
        ((int*)ws)[META + r]            = cnt_sh;        // p
        ws[META + 64 + r]               = tval;
        ((unsigned*)ws)[META + 128 + r] = 0xFFFFFFFFu;   // mr sentinel (+max key)
    }
}

// ===================== K2: min-max at position p ============================
__global__ __launch_bounds__(NTH2) void k2_minmax(
    const float* __restrict__ ws, unsigned* __restrict__ mr)
{
    __shared__ float Sloc[N];    // S[p+1 .. N]
    __shared__ float rtab[N];    // 1/(d+1)
    __shared__ float maxh[NTH2];

    const int r  = blockIdx.y;
    const int m  = blockIdx.x;
    const int t  = threadIdx.x;
    const int p  = ((const int*)ws)[META + r];
    const int j0 = m * 64;
    if (j0 > p) return;                        // idle slices exit immediately
    const int len = N - p;
    const float* Srow = ws + r * SROW;

    const int jl = t & 63;
    const int j  = j0 + jl;
    const float Sj = (j <= p) ? Srow[j] : 0.0f;   // hoisted global load

    for (int i = t; i < len; i += NTH2) Sloc[i] = Srow[p + 1 + i];
    for (int d = t; d < N; d += NTH2) rtab[d] = 1.0f / (float)(d + 1);
    __syncthreads();

    const int q  = t >> 6;                 // wave-uniform k-quarter
    const int k0 = (q * len) >> 2;
    const int k1 = ((q + 1) * len) >> 2;
    float maxv = -INFINITY;
    if (j <= p) {
        const float* sp = &Sloc[k0];       // wave-uniform addr -> broadcast
        const float* rp = &rtab[p + k0 - j];  // stride-1 across lanes
        float c = 0.5f * (float)(j + p + k0) - (float)N;  // (j+k)/2 - N
        #pragma unroll 8
        for (int it = 0; it < k1 - k0; ++it) {
            float mval = fmaf(sp[it] - Sj, rp[it], c);
            maxv = fmaxf(maxv, mval);
            c += 0.5f;                     // exact (multiples of 0.5)
        }
    }
    maxh[t] = maxv;
    __syncthreads();
    if (t < 64) {                          // combine quarters + min-reduce
        float mv = fmaxf(fmaxf(maxh[t], maxh[t + 64]),
                         fmaxf(maxh[t + 128], maxh[t + 192]));
        float minv = (j0 + t <= p) ? mv : INFINITY;
        #pragma unroll
        for (int off = 32; off; off >>= 1)
            minv = fminf(minv, __shfl_down(minv, off));
        if (t == 0) atomicMin(&mr[r], fkey(minv));
    }
}

// ===================== K3: loss + mean ======================================
__global__ __launch_bounds__(64) void k3_loss(
    const unsigned* __restrict__ mr, const float* __restrict__ tv,
    float* __restrict__ out, int nrows)
{
    int t = threadIdx.x;
    float loss = 0.0f;
    if (t < nrows) {
        float sol  = fdecode(mr[t]);
        float rank = tv[t] - sol;
        loss = fmaxf(0.0f, (float)(N - 5 + 1) - rank);
    }
    #pragma unroll
    for (int off = 32; off; off >>= 1) loss += __shfl_down(loss, off);
    if (t == 0) out[0] = loss / (float)nrows;
}

// ===================== fallback: monolithic (R4) ============================
__global__ __launch_bounds__(NTH1) void topk_loss_mono(
    const float* __restrict__ mat, const int* __restrict__ target,
    float* __restrict__ d_out, int nrows)
{
    __shared__ float S[1025];
    __shared__ float rcp[N];
    __shared__ float sx[1024];
    __shared__ float wtot[8];
    __shared__ float red[8];
    __shared__ int   cnt_sh;

    const int tid  = threadIdx.x;
    const int lane = tid & 63;
    const int w    = tid >> 6;
    const int i0   = (w << 7) + lane;
    const int i1   = i0 + 64;
    const float* row = mat + blockIdx.x * N;
    const int   tgt  = target[blockIdx.x];
    const float tval = row[tgt];

    float r0 = row[i0];
    float r1 = (i1 < N) ? row[i1] : -INFINITY;
    if (tid == 0) cnt_sh = 0;
    rcp[tid] = 1.0f / (float)(tid + 1);
    if (tid + NTH1 < N) rcp[tid + NTH1] = 1.0f / (float)(tid + NTH1 + 1);

    int lc = ((r0 > tval) || (r0 == tval && i0 < tgt))
           + ((r1 > tval) || (r1 == tval && i1 < tgt));
    #pragma unroll
    for (int off = 32; off; off >>= 1) lc += __shfl_down(lc, off);
    __syncthreads();
    if (lane == 0 && lc) atomicAdd(&cnt_sh, lc);

    auto cas_shfl = [&](float& rr, int i, unsigned k, unsigned j) {
        float o = __shfl_xor(rr, (int)j);
        bool lower = ((lane & (int)j) == 0);
        bool desc  = ((i & (int)k) == 0);
        rr = (lower == desc) ? fmaxf(rr, o) : fminf(rr, o);
    };
    #pragma unroll
    for (unsigned k = 2; k <= 64; k <<= 1)
        #pragma unroll
        for (unsigned j = k >> 1; j; j >>= 1) { cas_shfl(r0, i0, k, j); cas_shfl(r1, i1, k, j); }
    #pragma unroll
    for (unsigned k = 128; k <= 1024; k <<= 1) {
        #pragma unroll
        for (unsigned j = k >> 1; j >= 128; j >>= 1) {
            __syncthreads();
            sx[i0] = r0; sx[i1] = r1;
            __syncthreads();
            float o0 = sx[i0 ^ (int)j], o1 = sx[i1 ^ (int)j];
            bool lower = ((i0 & (int)j) == 0);
            bool desc  = ((i0 & (int)k) == 0);
            r0 = (lower == desc) ? fmaxf(r0, o0) : fminf(r0, o0);
            r1 = (lower == desc) ? fmaxf(r1, o1) : fminf(r1, o1);
        }
        {
            bool desc = ((i0 & (int)k) == 0);
            float a = fmaxf(r0, r1), b = fminf(r0, r1);
            r0 = desc ? a : b;
            r1 = desc ? b : a;
        }
        #pragma unroll
        for (unsigned j = 32; j; j >>= 1) { cas_shfl(r0, i0, k, j); cas_shfl(r1, i1, k, j); }
    }

    if (i1 >= N) r1 = 0.0f;
    float incl0 = r0;
    #pragma unroll
    for (int off = 1; off < 64; off <<= 1) {
        float y = __shfl_up(incl0, off);
        if (lane >= off) incl0 += y;
    }
    float tot0 = __shfl(incl0, 63);
    float incl1 = r1;
    #pragma unroll
    for (int off = 1; off < 64; off <<= 1) {
        float y = __shfl_up(incl1, off);
        if (lane >= off) incl1 += y;
    }
    if (lane == 63) wtot[w] = incl0 + incl1;
    __syncthreads();
    float base = 0.0f;
    #pragma unroll
    for (int u = 0; u < 8; ++u) { float t = wtot[u]; if (u < w) base += t; }
    if (tid == 0) S[0] = 0.0f;
    S[i0 + 1] = base + incl0;
    S[i1 + 1] = base + tot0 + incl1;
    __syncthreads();

    const int p   = cnt_sh;
    const int len = N - p;
    float minv = INFINITY;
    for (int j = tid; j <= p; j += NTH1) {
        const float  Sj = S[j];
        const float* Sp = &S[p + 1];
        const float* rp = &rcp[p - j];
        const float  cj = 0.5f * (float)(j + p) - (float)N;
        float maxv = -INFINITY;
        #pragma unroll 8
        for (int it = 0; it < len; ++it) {
            float mm = fmaf(Sp[it] - Sj, rp[it], cj + 0.5f * (float)it);
            maxv = fmaxf(maxv, mm);
        }
        minv = fminf(minv, maxv);
    }
    #pragma unroll
    for (int off = 32; off; off >>= 1) minv = fminf(minv, __shfl_down(minv, off));
    if (lane == 0) red[w] = minv;
    __syncthreads();
    if (tid == 0) {
        float sol = red[0];
        #pragma unroll
        for (int u = 1; u < 8; ++u) sol = fminf(sol, red[u]);
        float rank_label = tval - sol;
        float loss = fmaxf(0.0f, (float)(N - 5 + 1) - rank_label);
        atomicAdd(d_out, loss / (float)nrows);
    }
}

extern "C" void kernel_launch(void* const* d_in, const int* in_sizes, int n_in,
                              void* d_out, int out_size, void* d_ws, size_t ws_size,
                              hipStream_t stream) {
    (void)n_in;
    const float* mat    = (const float*)d_in[0];
    const int*   target = (const int*)d_in[1];
    float*       out    = (float*)d_out;
    const int    nrows  = in_sizes[1];   // 64

    const size_t need = (size_t)(META + 256) * sizeof(float);
    if (nrows == 64 && ws_size >= need) {
        float*    ws = (float*)d_ws;
        int*      pw = (int*)(ws + META);        (void)pw;
        float*    tv = ws + META + 64;
        unsigned* mr = (unsigned*)(ws + META + 128);
        k1_sort_scan<<<nrows, NTH1, 0, stream>>>(mat, target, ws);
        dim3 g2(MSLICE, nrows);
        k2_minmax<<<g2, NTH2, 0, stream>>>(ws, mr);
        k3_loss<<<1, 64, 0, stream>>>(mr, tv, out, nrows);
    } else {
        hipMemsetAsync(out, 0, sizeof(float) * out_size, stream);
        topk_loss_mono<<<nrows, NTH1, 0, stream>>>(mat, target, out, nrows);
    }
}